// Round 7
// baseline (497.400 us; speedup 1.0000x reference)
//
#include <hip/hip_runtime.h>
#include <hip/hip_bf16.h>
#include <stdint.h>

// Problem constants (CZT_72533407694901)
#define MM   1840          // M (zoom bins)
#define M2   3680          // 2M rows of W / X
#define NN   512           // N time samples
#define K2   1024          // 2N columns of W
#define CS   8192          // C*S = 32*256
#define MPAD 3712          // Abf row padding (rows 3680..3711 zero-filled by prep)

#define WPREP_BLOCKS (MPAD / 2)        // 1856 blocks, 2 rows each
#define XT_NB        (CS / 32)         // 256 n-tiles
#define XT_KB        (NN / 64)         // 8 k-tiles

#define GBM 128
#define GBN 256
#define NBM 29             // 29*128 = 3712 = MPAD exactly
#define NBN 32             // 8192/256
#define NKT 8              // K=512 / BK=64

// MEASUREMENT ROUND #3: in-kernel repetition so both kernels out-last the
// ~81us harness fills and surface in the top-5 with full counters.
// Bodies are byte-identical to the R6 build (181.3us best); reps are
// idempotent; asm memory clobber blocks cross-rep CSE.
#define REP_GEMM 3         // ~37.3us x3 ~ 111us  -> top-5 rank 1
#define REP_PREP 7         // ~13.6us x7 ~  95us  -> top-5 rank 2

typedef __bf16 bf16x8 __attribute__((ext_vector_type(8)));
typedef float  floatx4 __attribute__((ext_vector_type(4)));

// -------------------------------------------------------------------------
// Session ledger (measured): fixed ~130.4us | prep 13.6us | gemm 37.3us.
// gemm floor ~21us (write 18.6 @ fill-comparator 6.5TB/s + reads ~2-3).
// R4 occupancy theory: predicted -13, got -1.8.  R5 store-granularity
// theory: predicted -15, got -1.5.  Both falsified -> this round buys
// direct per-kernel counters (WRITE_SIZE / FETCH_SIZE / MfmaUtil /
// VALUBusy / LDS_CONFLICT) instead of a third guess.
// -------------------------------------------------------------------------

// -------------------------------------------------------------------------
// Kernel 1 (fused prep) — body identical to R6; outer rep loop added.
// -------------------------------------------------------------------------
__global__ __launch_bounds__(256) void czt_prep(const float* __restrict__ Wr,
                                                const float* __restrict__ Wi,
                                                const float* __restrict__ ac,
                                                const float* __restrict__ as_,
                                                const float* __restrict__ x,
                                                float* __restrict__ Wout,
                                                __hip_bfloat16* __restrict__ Abf,
                                                __hip_bfloat16* __restrict__ Bxt) {
    __shared__ float tile[64 * 33];
    const int b   = blockIdx.x;
    const int tid = threadIdx.x;

#pragma unroll 1
    for (int rep = 0; rep < REP_PREP; ++rep) {
        asm volatile("" ::: "memory");     // block cross-rep CSE
        if (b < WPREP_BLOCKS) {
            const int j = b * 2 + (tid >> 7);
            const int k = (tid & 127) * 4;

            union { __hip_bfloat16 h[4]; uint2 u; } p;
            if (j < M2) {
                const int jj = (j < MM) ? j : j - MM;
                const floatx4 wr = *(const floatx4*)&Wr[(size_t)jj * NN + k];
                const floatx4 wi = *(const floatx4*)&Wi[(size_t)jj * NN + k];
                const floatx4 c  = *(const floatx4*)&ac[k];
                const floatx4 s  = *(const floatx4*)&as_[k];
                floatx4 f, g, a;
                if (j < MM) { f = wr; g = -wi; a = wr * c - wi * s; }
                else        { f = wi; g = wr;  a = wi * c + wr * s; }
#pragma unroll
                for (int e = 0; e < 4; ++e) {
                    f[e] = fminf(1.f, fmaxf(-1.f, f[e]));
                    g[e] = fminf(1.f, fmaxf(-1.f, g[e]));
                }
                *(floatx4*)&Wout[(size_t)j * K2 + k]      = f;
                *(floatx4*)&Wout[(size_t)j * K2 + NN + k] = g;
                p.h[0] = __float2bfloat16(a[0]);
                p.h[1] = __float2bfloat16(a[1]);
                p.h[2] = __float2bfloat16(a[2]);
                p.h[3] = __float2bfloat16(a[3]);
            } else {
                p.h[0] = p.h[1] = p.h[2] = p.h[3] = __float2bfloat16(0.0f);
            }
            *(uint2*)&Abf[(size_t)j * NN + k] = p.u;
        } else {
            __syncthreads();               // tile reuse across reps (uniform)
            const int tb = b - WPREP_BLOCKS;
            const int n0 = (tb & (XT_NB - 1)) * 32;
            const int k0 = (tb >> 8) * 64;

            const int row = tid >> 2;
            const int c8  = (tid & 3) * 8;
            const floatx4* src = (const floatx4*)&x[(size_t)(k0 + row) * CS + n0 + c8];
            const floatx4 v0 = src[0];
            const floatx4 v1 = src[1];
            float* tr = &tile[row * 33 + c8];
            tr[0] = v0[0]; tr[1] = v0[1]; tr[2] = v0[2]; tr[3] = v0[3];
            tr[4] = v1[0]; tr[5] = v1[1]; tr[6] = v1[2]; tr[7] = v1[3];
            __syncthreads();

            const int oc = tid & 7;
            const int nr = tid >> 3;
            union { __hip_bfloat16 h[8]; uint4 u; } q;
#pragma unroll
            for (int jj = 0; jj < 8; ++jj)
                q.h[jj] = __float2bfloat16(tile[(oc * 8 + jj) * 33 + nr]);
            *(uint4*)&Bxt[(size_t)(n0 + nr) * NN + k0 + oc * 8] = q.u;
        }
    }
}

// -------------------------------------------------------------------------
// Kernel 2: GEMM — body identical to R6; outer rep loop added.
// -------------------------------------------------------------------------
__device__ __forceinline__ void gload_lds16(const void* g, void* l) {
    __builtin_amdgcn_global_load_lds(
        (const __attribute__((address_space(1))) uint32_t*)g,
        (__attribute__((address_space(3))) uint32_t*)l,
        16, 0, 0);
}

__device__ __forceinline__ void lds_fence() {
    asm volatile("s_waitcnt lgkmcnt(0)" ::: "memory");
    __builtin_amdgcn_sched_barrier(0);
}

__global__ __launch_bounds__(512, 4) void czt_gemm(const __hip_bfloat16* __restrict__ Abf,
                                                   const __hip_bfloat16* __restrict__ Bxt,
                                                   float* __restrict__ Xout) {
    __shared__ alignas(16) char smem[GBM * 64 * 2 + GBN * 64 * 2];
    __hip_bfloat16* As = (__hip_bfloat16*)smem;                 // [128*64]
    __hip_bfloat16* Bs = (__hip_bfloat16*)(smem + GBM * 64 * 2);// [256*64]

    const int tid  = threadIdx.x;
    const int lane = tid & 63;
    const int w    = tid >> 6;
    const int quad = lane >> 4;
    const int r16  = lane & 15;

    const int b  = blockIdx.x;
    const int wk = (b & 7) * 116 + (b >> 3);
    const int mb = wk % NBM;
    const int nb = wk / NBM;
    const int mtile = mb * GBM;
    const int ntile = nb * GBN;

    const int wm = (w >> 2) * 64;
    const int wn = (w & 3) * 64;

    const int rsub   = lane >> 3;
    const int cstage = ((lane & 7) ^ rsub) * 8;

    const __hip_bfloat16* Ag = Abf + (size_t)(mtile + w * 16 + rsub) * NN + cstage;
    const __hip_bfloat16* Bg = Bxt + (size_t)(ntile + w * 32 + rsub) * NN + cstage;

#pragma unroll 1
    for (int rep = 0; rep < REP_GEMM; ++rep) {
        asm volatile("" ::: "memory");     // block cross-rep CSE
        floatx4 acc[4][4] = {};

#pragma unroll
        for (int kt = 0; kt < NKT; ++kt) {
            __syncthreads();
#pragma unroll
            for (int t = 0; t < 2; ++t)
                gload_lds16(Ag + (size_t)(t * 8) * NN + kt * 64,
                            &As[(w * 16 + t * 8) * 64]);
#pragma unroll
            for (int t = 0; t < 4; ++t)
                gload_lds16(Bg + (size_t)(t * 8) * NN + kt * 64,
                            &Bs[(w * 32 + t * 8) * 64]);
            __syncthreads();

#pragma unroll
            for (int ks = 0; ks < 2; ++ks) {
                const int pch = ((ks * 4 + quad) ^ (r16 & 7)) * 8;
                bf16x8 af[4], bv[4];
#pragma unroll
                for (int m = 0; m < 4; ++m)
                    af[m] = *(const bf16x8*)&As[(wm + m * 16 + r16) * 64 + pch];
#pragma unroll
                for (int n = 0; n < 4; ++n)
                    bv[n] = *(const bf16x8*)&Bs[(wn + n * 16 + r16) * 64 + pch];
#pragma unroll
                for (int m = 0; m < 4; ++m)
#pragma unroll
                    for (int n = 0; n < 4; ++n)
                        acc[m][n] = __builtin_amdgcn_mfma_f32_16x16x32_bf16(
                            af[m], bv[n], acc[m][n], 0, 0, 0);
            }
        }

        // ---- LDS-transpose epilogue (dwordx4 stores) ----
        __syncthreads();                   // retire all K-loop LDS reads
        float* ep = (float*)smem + (size_t)w * 1024;

#pragma unroll
        for (int m = 0; m < 4; ++m) {
            const int rbase = mtile + wm + m * 16;
#pragma unroll
            for (int n = 0; n < 4; ++n)
#pragma unroll
                for (int rr = 0; rr < 4; ++rr) {
                    const int row16 = quad * 4 + rr;
                    const int pcol  = (n * 16 + r16) ^ (quad << 4);
                    ep[row16 * 64 + pcol] = acc[m][n][rr];
                }
            lds_fence();
            if (rbase < M2) {
#pragma unroll
                for (int sub = 0; sub < 4; ++sub) {
                    const int row16 = quad + sub * 4;
                    const int pcol  = (r16 * 4) ^ (sub << 4);
                    const floatx4 v = *(const floatx4*)&ep[row16 * 64 + pcol];
                    *(floatx4*)&Xout[(size_t)(rbase + row16) * CS + ntile + wn + r16 * 4] = v;
                }
            }
            __builtin_amdgcn_sched_barrier(0);
        }
        // next rep's kt=0 __syncthreads orders epilogue LDS reads vs re-stage
    }
}

// -------------------------------------------------------------------------
extern "C" void kernel_launch(void* const* d_in, const int* in_sizes, int n_in,
                              void* d_out, int out_size, void* d_ws, size_t ws_size,
                              hipStream_t stream) {
    const float* x   = (const float*)d_in[0];   // [512, 32, 256]
    const float* Wr  = (const float*)d_in[1];   // [1840, 512]
    const float* Wi  = (const float*)d_in[2];   // [1840, 512]
    const float* ac  = (const float*)d_in[3];   // [512]
    const float* as_ = (const float*)d_in[4];   // [512]

    float* Wout = (float*)d_out;                       // [3680, 1024]
    float* Xout = (float*)d_out + (size_t)M2 * K2;     // [3680, 8192]

    __hip_bfloat16* Abf = (__hip_bfloat16*)d_ws;                                  // [3712, 512]
    __hip_bfloat16* Bxt = (__hip_bfloat16*)((char*)d_ws + (size_t)MPAD * NN * 2); // [8192, 512]

    czt_prep<<<dim3(WPREP_BLOCKS + XT_NB * XT_KB), dim3(256), 0, stream>>>(
        Wr, Wi, ac, as_, x, Wout, Abf, Bxt);
    czt_gemm<<<dim3(NBM * NBN), dim3(512), 0, stream>>>(Abf, Bxt, Xout);
}

// Round 8
// 180.798 us; speedup vs baseline: 2.7511x; 2.7511x over previous
//
#include <hip/hip_runtime.h>
#include <hip/hip_bf16.h>
#include <stdint.h>

// Problem constants (CZT_72533407694901)
#define MM   1840          // M (zoom bins)
#define M2   3680          // 2M rows of W / X
#define NN   512           // N time samples
#define K2   1024          // 2N columns of W
#define CS   8192          // C*S = 32*256
#define MPAD 3712          // Abf row padding (rows 3680..3711 zero-filled by prep)

#define WPREP_BLOCKS (MPAD / 2)        // 1856 blocks, 2 rows each
#define XT_NB        (CS / 32)         // 256 n-tiles
#define XT_KB        (NN / 64)         // 8 k-tiles

#define GBM 128
#define GBN 256
#define NBM 29             // 29*128 = 3712 = MPAD exactly
#define NBN 32             // 8192/256
#define NKT 8              // K=512 / BK=64

typedef __bf16 bf16x8 __attribute__((ext_vector_type(8)));
typedef float  floatx4 __attribute__((ext_vector_type(4)));

// -------------------------------------------------------------------------
// Session ledger (measured):
//   fixed ~130.4us | prep 13.6us | gemm 37.3us (floor ~21us).
// R7 direct counters (gemm x3-rep dispatch): MfmaUtil 10.7, VALU 3.4,
// LDS_CONFLICT 0, hbm 3.37TB/s = 42% peak. Both real run (140MB @ 3.75)
// and rep regime (379MB @ 3.37) show the same sustained-BW deficit vs
// fill 6.5 / copy 6.3 TB/s. Remaining structural difference: write page
// locality (1-KB chunks, 32-KB stride, mb-fastest order = whole-surface
// spray). ROUND 7 CHANGE: nb-fastest / mb-slowest tile map -> concurrent
// blocks per XCD fill 4 adjacent n-slabs over a sliding row window.
// Everything else byte-identical to the R6 build; REPs back to 1.
// -------------------------------------------------------------------------

// -------------------------------------------------------------------------
// Kernel 1 (fused prep) — unchanged (verified).
// -------------------------------------------------------------------------
__global__ __launch_bounds__(256) void czt_prep(const float* __restrict__ Wr,
                                                const float* __restrict__ Wi,
                                                const float* __restrict__ ac,
                                                const float* __restrict__ as_,
                                                const float* __restrict__ x,
                                                float* __restrict__ Wout,
                                                __hip_bfloat16* __restrict__ Abf,
                                                __hip_bfloat16* __restrict__ Bxt) {
    __shared__ float tile[64 * 33];
    const int b   = blockIdx.x;
    const int tid = threadIdx.x;

    if (b < WPREP_BLOCKS) {
        const int j = b * 2 + (tid >> 7);
        const int k = (tid & 127) * 4;

        union { __hip_bfloat16 h[4]; uint2 u; } p;
        if (j < M2) {
            const int jj = (j < MM) ? j : j - MM;
            const floatx4 wr = *(const floatx4*)&Wr[(size_t)jj * NN + k];
            const floatx4 wi = *(const floatx4*)&Wi[(size_t)jj * NN + k];
            const floatx4 c  = *(const floatx4*)&ac[k];
            const floatx4 s  = *(const floatx4*)&as_[k];
            floatx4 f, g, a;
            if (j < MM) { f = wr; g = -wi; a = wr * c - wi * s; }
            else        { f = wi; g = wr;  a = wi * c + wr * s; }
#pragma unroll
            for (int e = 0; e < 4; ++e) {
                f[e] = fminf(1.f, fmaxf(-1.f, f[e]));
                g[e] = fminf(1.f, fmaxf(-1.f, g[e]));
            }
            *(floatx4*)&Wout[(size_t)j * K2 + k]      = f;
            *(floatx4*)&Wout[(size_t)j * K2 + NN + k] = g;
            p.h[0] = __float2bfloat16(a[0]);
            p.h[1] = __float2bfloat16(a[1]);
            p.h[2] = __float2bfloat16(a[2]);
            p.h[3] = __float2bfloat16(a[3]);
        } else {
            p.h[0] = p.h[1] = p.h[2] = p.h[3] = __float2bfloat16(0.0f);
        }
        *(uint2*)&Abf[(size_t)j * NN + k] = p.u;
    } else {
        const int tb = b - WPREP_BLOCKS;
        const int n0 = (tb & (XT_NB - 1)) * 32;
        const int k0 = (tb >> 8) * 64;

        const int row = tid >> 2;
        const int c8  = (tid & 3) * 8;
        const floatx4* src = (const floatx4*)&x[(size_t)(k0 + row) * CS + n0 + c8];
        const floatx4 v0 = src[0];
        const floatx4 v1 = src[1];
        float* tr = &tile[row * 33 + c8];
        tr[0] = v0[0]; tr[1] = v0[1]; tr[2] = v0[2]; tr[3] = v0[3];
        tr[4] = v1[0]; tr[5] = v1[1]; tr[6] = v1[2]; tr[7] = v1[3];
        __syncthreads();

        const int oc = tid & 7;
        const int nr = tid >> 3;
        union { __hip_bfloat16 h[8]; uint4 u; } q;
#pragma unroll
        for (int jj = 0; jj < 8; ++jj)
            q.h[jj] = __float2bfloat16(tile[(oc * 8 + jj) * 33 + nr]);
        *(uint4*)&Bxt[(size_t)(n0 + nr) * NN + k0 + oc * 8] = q.u;
    }
}

// -------------------------------------------------------------------------
// Kernel 2: GEMM — body identical to R6 except the block->tile map.
// -------------------------------------------------------------------------
__device__ __forceinline__ void gload_lds16(const void* g, void* l) {
    __builtin_amdgcn_global_load_lds(
        (const __attribute__((address_space(1))) uint32_t*)g,
        (__attribute__((address_space(3))) uint32_t*)l,
        16, 0, 0);
}

__device__ __forceinline__ void lds_fence() {
    asm volatile("s_waitcnt lgkmcnt(0)" ::: "memory");
    __builtin_amdgcn_sched_barrier(0);
}

__global__ __launch_bounds__(512, 4) void czt_gemm(const __hip_bfloat16* __restrict__ Abf,
                                                   const __hip_bfloat16* __restrict__ Bxt,
                                                   float* __restrict__ Xout) {
    __shared__ alignas(16) char smem[GBM * 64 * 2 + GBN * 64 * 2];
    __hip_bfloat16* As = (__hip_bfloat16*)smem;                 // [128*64]
    __hip_bfloat16* Bs = (__hip_bfloat16*)(smem + GBM * 64 * 2);// [256*64]

    const int tid  = threadIdx.x;
    const int lane = tid & 63;
    const int w    = tid >> 6;
    const int quad = lane >> 4;
    const int r16  = lane & 15;

    // Write-locality tile map (R7): XCD g = b&7 owns 4 ADJACENT n-slabs
    // (cols [g*1024, g*1024+1024)); within XCD, nb is FASTEST and mb
    // SLOWEST, so concurrent blocks fill adjacent 1-KB col-chunks of the
    // same rows (4-KB bands) over a sliding 16-mb row window, instead of
    // spraying 1-KB chunks across all 3712 rows (page thrash).
    // Bijection: b = mb*32 + nbl*8 + g.
    const int b   = blockIdx.x;
    const int g   = b & 7;
    const int i   = b >> 3;           // 0..115
    const int nbl = i & 3;            // n-slab within XCD (fastest)
    const int mb  = i >> 2;           // 0..28 (slowest)
    const int nb  = g * 4 + nbl;
    const int mtile = mb * GBM;
    const int ntile = nb * GBN;

    const int wm = (w >> 2) * 64;
    const int wn = (w & 3) * 64;

    const int rsub   = lane >> 3;
    const int cstage = ((lane & 7) ^ rsub) * 8;

    const __hip_bfloat16* Ag = Abf + (size_t)(mtile + w * 16 + rsub) * NN + cstage;
    const __hip_bfloat16* Bg = Bxt + (size_t)(ntile + w * 32 + rsub) * NN + cstage;

    floatx4 acc[4][4] = {};

#pragma unroll
    for (int kt = 0; kt < NKT; ++kt) {
        __syncthreads();
#pragma unroll
        for (int t = 0; t < 2; ++t)
            gload_lds16(Ag + (size_t)(t * 8) * NN + kt * 64,
                        &As[(w * 16 + t * 8) * 64]);
#pragma unroll
        for (int t = 0; t < 4; ++t)
            gload_lds16(Bg + (size_t)(t * 8) * NN + kt * 64,
                        &Bs[(w * 32 + t * 8) * 64]);
        __syncthreads();

#pragma unroll
        for (int ks = 0; ks < 2; ++ks) {
            const int pch = ((ks * 4 + quad) ^ (r16 & 7)) * 8;
            bf16x8 af[4], bv[4];
#pragma unroll
            for (int m = 0; m < 4; ++m)
                af[m] = *(const bf16x8*)&As[(wm + m * 16 + r16) * 64 + pch];
#pragma unroll
            for (int n = 0; n < 4; ++n)
                bv[n] = *(const bf16x8*)&Bs[(wn + n * 16 + r16) * 64 + pch];
#pragma unroll
            for (int m = 0; m < 4; ++m)
#pragma unroll
                for (int n = 0; n < 4; ++n)
                    acc[m][n] = __builtin_amdgcn_mfma_f32_16x16x32_bf16(
                        af[m], bv[n], acc[m][n], 0, 0, 0);
        }
    }

    // ---- LDS-transpose epilogue (dwordx4 stores) ----
    __syncthreads();                       // retire all K-loop LDS reads
    float* ep = (float*)smem + (size_t)w * 1024;

#pragma unroll
    for (int m = 0; m < 4; ++m) {
        const int rbase = mtile + wm + m * 16;
#pragma unroll
        for (int n = 0; n < 4; ++n)
#pragma unroll
            for (int rr = 0; rr < 4; ++rr) {
                const int row16 = quad * 4 + rr;
                const int pcol  = (n * 16 + r16) ^ (quad << 4);
                ep[row16 * 64 + pcol] = acc[m][n][rr];
            }
        lds_fence();
        if (rbase < M2) {
#pragma unroll
            for (int sub = 0; sub < 4; ++sub) {
                const int row16 = quad + sub * 4;
                const int pcol  = (r16 * 4) ^ (sub << 4);
                const floatx4 v = *(const floatx4*)&ep[row16 * 64 + pcol];
                *(floatx4*)&Xout[(size_t)(rbase + row16) * CS + ntile + wn + r16 * 4] = v;
            }
        }
        __builtin_amdgcn_sched_barrier(0);
    }
}

// -------------------------------------------------------------------------
extern "C" void kernel_launch(void* const* d_in, const int* in_sizes, int n_in,
                              void* d_out, int out_size, void* d_ws, size_t ws_size,
                              hipStream_t stream) {
    const float* x   = (const float*)d_in[0];   // [512, 32, 256]
    const float* Wr  = (const float*)d_in[1];   // [1840, 512]
    const float* Wi  = (const float*)d_in[2];   // [1840, 512]
    const float* ac  = (const float*)d_in[3];   // [512]
    const float* as_ = (const float*)d_in[4];   // [512]

    float* Wout = (float*)d_out;                       // [3680, 1024]
    float* Xout = (float*)d_out + (size_t)M2 * K2;     // [3680, 8192]

    __hip_bfloat16* Abf = (__hip_bfloat16*)d_ws;                                  // [3712, 512]
    __hip_bfloat16* Bxt = (__hip_bfloat16*)((char*)d_ws + (size_t)MPAD * NN * 2); // [8192, 512]

    czt_prep<<<dim3(WPREP_BLOCKS + XT_NB * XT_KB), dim3(256), 0, stream>>>(
        Wr, Wi, ac, as_, x, Wout, Abf, Bxt);
    czt_gemm<<<dim3(NBM * NBN), dim3(512), 0, stream>>>(Abf, Bxt, Xout);
}